// Round 1
// baseline (3037.140 us; speedup 1.0000x reference)
//
#include <hip/hip_runtime.h>
#include <stdint.h>

// SkipGRU: T=384, B=48, C=H=256, L=2.
// Plan: GEMM(gi = x@W_ih^T + b_ih) -> pairwise-WG recurrence -> GEMM -> recurrence.
// Recurrence: 2 WGs per batch element; each WG holds half of W_hh (384 KB) in
// REGISTERS (48 float4/lane @ 512 threads) and computes r/z/n rows for 128 of the
// 256 h-columns. Per-step exchange of the 128-float h-half + partial lw-dot via
// device-scope atomics + a release/acquire flag handshake. Skip steps need no
// matvec and no sync (state replicated bit-exactly in both WGs).

#define T_STEPS 384
#define BATCH   48
#define HID     256
#define G3      768

__device__ __forceinline__ float sigm_(float x) { return 1.f / (1.f + __expf(-x)); }
__device__ __forceinline__ float tanh_(float x) {
    float ax = fabsf(x);
    float e  = __expf(-2.f * ax);
    float r  = (1.f - e) / (1.f + e);
    return copysignf(r, x);
}

// ---------------------------------------------------------------------------
// GEMM: O[m][n] = sum_k X[m][k] * W[n][k] + B[n];  M=18432, N=768, K=256.
// grid (12, 144), block 256. Tile 128(M) x 64(N), K-chunks of 32 staged in LDS.
// ---------------------------------------------------------------------------
__global__ __launch_bounds__(256, 2) void gemm_nt(const float* __restrict__ X,
                                                  const float* __restrict__ W,
                                                  const float* __restrict__ B,
                                                  float* __restrict__ O)
{
    __shared__ float As[32 * 140];  // [k][m], stride 140 (16B-aligned rows, de-conflicted)
    __shared__ float Bs[32 * 68];   // [k][n], stride 68

    const int tid = threadIdx.x;
    const int tx  = tid & 15;   // n quad
    const int ty  = tid >> 4;   // m octet
    const int n0  = blockIdx.x * 64;
    const int m0  = blockIdx.y * 128;

    float acc[8][4];
#pragma unroll
    for (int i = 0; i < 8; ++i)
#pragma unroll
        for (int j = 0; j < 4; ++j) acc[i][j] = 0.f;

    const float4 bias4 = *reinterpret_cast<const float4*>(B + n0 + tx * 4);

    for (int kc = 0; kc < 8; ++kc) {
        const int k0 = kc * 32;
        float4 a[4], bb[2];
#pragma unroll
        for (int j = 0; j < 4; ++j) {
            int f = tid + 256 * j, r = f >> 3, cq = f & 7;
            a[j] = *reinterpret_cast<const float4*>(X + (size_t)(m0 + r) * 256 + k0 + cq * 4);
        }
#pragma unroll
        for (int j = 0; j < 2; ++j) {
            int f = tid + 256 * j, r = f >> 3, cq = f & 7;
            bb[j] = *reinterpret_cast<const float4*>(W + (size_t)(n0 + r) * 256 + k0 + cq * 4);
        }
        __syncthreads();  // previous chunk's compute done before LDS overwrite
#pragma unroll
        for (int j = 0; j < 4; ++j) {
            int f = tid + 256 * j, r = f >> 3, cq = f & 7;
            As[(cq * 4 + 0) * 140 + r] = a[j].x;
            As[(cq * 4 + 1) * 140 + r] = a[j].y;
            As[(cq * 4 + 2) * 140 + r] = a[j].z;
            As[(cq * 4 + 3) * 140 + r] = a[j].w;
        }
#pragma unroll
        for (int j = 0; j < 2; ++j) {
            int f = tid + 256 * j, r = f >> 3, cq = f & 7;
            Bs[(cq * 4 + 0) * 68 + r] = bb[j].x;
            Bs[(cq * 4 + 1) * 68 + r] = bb[j].y;
            Bs[(cq * 4 + 2) * 68 + r] = bb[j].z;
            Bs[(cq * 4 + 3) * 68 + r] = bb[j].w;
        }
        __syncthreads();
#pragma unroll 8
        for (int kk = 0; kk < 32; ++kk) {
            float4 av0 = *reinterpret_cast<const float4*>(As + kk * 140 + ty * 8);
            float4 av1 = *reinterpret_cast<const float4*>(As + kk * 140 + ty * 8 + 4);
            float4 bv  = *reinterpret_cast<const float4*>(Bs + kk * 68 + tx * 4);
            float am[8] = {av0.x, av0.y, av0.z, av0.w, av1.x, av1.y, av1.z, av1.w};
            float bn[4] = {bv.x, bv.y, bv.z, bv.w};
#pragma unroll
            for (int i = 0; i < 8; ++i)
#pragma unroll
                for (int j = 0; j < 4; ++j) acc[i][j] = fmaf(am[i], bn[j], acc[i][j]);
        }
    }
#pragma unroll
    for (int i = 0; i < 8; ++i) {
        int row = m0 + ty * 8 + i;
        float4 o;
        o.x = acc[i][0] + bias4.x;
        o.y = acc[i][1] + bias4.y;
        o.z = acc[i][2] + bias4.z;
        o.w = acc[i][3] + bias4.w;
        *reinterpret_cast<float4*>(O + (size_t)row * 768 + n0 + tx * 4) = o;
    }
}

// ---------------------------------------------------------------------------
// Recurrence for one layer. grid = 96 (p = blk/48 in {0,1}, b = blk%48), block 512.
// WG p owns h-columns [p*128, p*128+128) and W_hh rows {c, 256+c, 512+c}.
// Wave w (0..7), group g = lane&15 -> column c = p*128 + w*16 + g.
// Sub s = lane>>4 -> k-slice [s*64, s*64+64); 3 rows x 16 float4 = 192 VGPRs of W.
// hbuf: 4 shifted copies of h (stride 264, shift 8 words) -> conflict-free b128 reads.
// ---------------------------------------------------------------------------
__global__ __launch_bounds__(512, 2) void rec_layer(
    const float* __restrict__ GI, float* __restrict__ Yout,
    const float* __restrict__ whh, const float* __restrict__ bhh,
    const float* __restrict__ lwl, const float* __restrict__ lbl,
    const float* __restrict__ hid,
    float* XH, float* PDX, int* FLG,
    float* __restrict__ hsout, float* __restrict__ tuout)
{
    __shared__ float hbuf[1056];  // 4 copies x 264
    __shared__ float pdw[8];
    __shared__ float pdslot;

    const int tid  = threadIdx.x;
    const int lane = tid & 63;
    const int w    = tid >> 6;
    const int g    = lane & 15;
    const int s    = lane >> 4;
    const int b    = blockIdx.x % 48;
    const int p    = blockIdx.x / 48;   // pair (i, i+48): likelier same XCD under round-robin
    const int q    = 1 - p;
    const int c    = p * 128 + w * 16 + g;

    // W_hh fragments -> registers (read-only, constant-indexed after full unroll)
    float4 Wr[16], Wz[16], Wn[16];
    {
        const float4* wr4 = reinterpret_cast<const float4*>(whh + (size_t)c * 256 + s * 64);
        const float4* wz4 = reinterpret_cast<const float4*>(whh + (size_t)(256 + c) * 256 + s * 64);
        const float4* wn4 = reinterpret_cast<const float4*>(whh + (size_t)(512 + c) * 256 + s * 64);
#pragma unroll
        for (int i = 0; i < 16; ++i) { Wr[i] = wr4[i]; Wz[i] = wz4[i]; Wn[i] = wn4[i]; }
    }

    const float bhr = bhh[c], bhz = bhh[256 + c], bhn = bhh[512 + c];
    const float lwc = lwl[c];
    const float lbv = lbl[0];

    if (tid < 256) {
        float v = hid[tid];
        hbuf[tid] = v; hbuf[264 + tid] = v; hbuf[528 + tid] = v; hbuf[792 + tid] = v;
    }
    __syncthreads();

    float u = 1.f, d = 0.f;
    bool  skip = false;
    int   ns = 0;  // count of non-skip (synced) steps; slot parity = ns&1

    float* XHb  = XH + b * 512;
    float* PDXb = PDX + b * 4;
    int*   FLGb = FLG + b * 2;

    for (int t = 0; t < T_STEPS; ++t) {
        const float bu  = rintf(u);        // jnp.round == RNE
        const float obu = 1.f - bu;
        const size_t yrow = ((size_t)t * 48 + b) * 256;

        if (skip) {
            // new_h = h*(1-bu); new_u = clip(u+d,0,1)*(1-bu); d unchanged; no sync needed.
            if (s == 0) {
                float hcv = hbuf[c];
                float nh  = hcv * obu;
                if (bu != 0.f) { hbuf[c] = nh; hbuf[264 + c] = nh; hbuf[528 + c] = nh; hbuf[792 + c] = nh; }
                Yout[yrow + c] = nh;
                if (t == T_STEPS - 1) hsout[b * 256 + c] = nh;
            }
            if (p == 0 && tid == 0) tuout[b * 768 + t] = bu;
            u    = fminf(fmaxf(u + d, 0.f), 1.f) * obu;
            skip = (u < 0.5f);
            __syncthreads();
        } else {
            const size_t gbase = ((size_t)t * 48 + b) * 768 + c;
            float gir = GI[gbase], giz = GI[gbase + 256], gin = GI[gbase + 512];

            float ar = 0.f, az = 0.f, an = 0.f;
            const float4* h4 = reinterpret_cast<const float4*>(hbuf + s * 328);  // s*264 + s*64
#pragma unroll
            for (int i = 0; i < 16; ++i) {
                float4 hv = h4[i];
                ar = fmaf(Wr[i].x, hv.x, ar); ar = fmaf(Wr[i].y, hv.y, ar);
                ar = fmaf(Wr[i].z, hv.z, ar); ar = fmaf(Wr[i].w, hv.w, ar);
                az = fmaf(Wz[i].x, hv.x, az); az = fmaf(Wz[i].y, hv.y, az);
                az = fmaf(Wz[i].z, hv.z, az); az = fmaf(Wz[i].w, hv.w, az);
                an = fmaf(Wn[i].x, hv.x, an); an = fmaf(Wn[i].y, hv.y, an);
                an = fmaf(Wn[i].z, hv.z, an); an = fmaf(Wn[i].w, hv.w, an);
            }
            ar += __shfl_xor(ar, 16); ar += __shfl_xor(ar, 32);
            az += __shfl_xor(az, 16); az += __shfl_xor(az, 32);
            an += __shfl_xor(an, 16); an += __shfl_xor(an, 32);

            float hcv = hbuf[s * 264 + c];  // old h[c]
            float rr  = sigm_(gir + ar + bhr);
            float zz  = sigm_(giz + az + bhz);
            float nn  = tanh_(gin + rr * (an + bhn));
            float nh  = ((1.f - zz) * nn + zz * hcv) * bu;  // h_ns == new_h (not skipping)
            float pdv = nh * lwc;

            __syncthreads();  // A: all matvec reads of hbuf done before updates
            if (s == 0) {
                hbuf[c] = nh; hbuf[264 + c] = nh; hbuf[528 + c] = nh; hbuf[792 + c] = nh;
                Yout[yrow + c] = nh;
                if (t == T_STEPS - 1) hsout[b * 256 + c] = nh;
                __hip_atomic_store(XHb + (ns & 1) * 256 + c, nh, __ATOMIC_RELAXED, __HIP_MEMORY_SCOPE_AGENT);
            }
            // exact wave butterfly: 4 identical copies per column -> 4*S, *0.25 exact
            pdv += __shfl_xor(pdv, 1);  pdv += __shfl_xor(pdv, 2);  pdv += __shfl_xor(pdv, 4);
            pdv += __shfl_xor(pdv, 8);  pdv += __shfl_xor(pdv, 16); pdv += __shfl_xor(pdv, 32);
            pdv *= 0.25f;
            if (lane == 0) pdw[w] = pdv;
            if (p == 0 && tid == 0) tuout[b * 768 + t] = bu;
            __syncthreads();  // B: pdw ready, all exchange stores drained (vmcnt at barrier)

            float ownpd = ((pdw[0] + pdw[1]) + (pdw[2] + pdw[3])) + ((pdw[4] + pdw[5]) + (pdw[6] + pdw[7]));
            if (tid == 0) {
                __hip_atomic_store(PDXb + (ns & 1) * 2 + p, ownpd, __ATOMIC_RELAXED, __HIP_MEMORY_SCOPE_AGENT);
                __hip_atomic_store(FLGb + p, ns + 1, __ATOMIC_RELEASE, __HIP_MEMORY_SCOPE_AGENT);
                while (__hip_atomic_load(FLGb + q, __ATOMIC_ACQUIRE, __HIP_MEMORY_SCOPE_AGENT) < ns + 1) {
                    __builtin_amdgcn_s_sleep(1);
                }
                pdslot = __hip_atomic_load(PDXb + (ns & 1) * 2 + q, __ATOMIC_RELAXED, __HIP_MEMORY_SCOPE_AGENT);
            }
            __syncthreads();  // C: partner's step visible
            if (tid < 128) {
                int qc  = q * 128 + tid;
                float v = __hip_atomic_load(XHb + (ns & 1) * 256 + qc, __ATOMIC_RELAXED, __HIP_MEMORY_SCOPE_AGENT);
                hbuf[qc] = v; hbuf[264 + qc] = v; hbuf[528 + qc] = v; hbuf[792 + qc] = v;
            }
            float dns = sigm_(ownpd + pdslot + lbv);  // commutative sum -> bit-identical in both WGs
            u = dns * bu; d = dns;
            skip = (u < 0.5f);
            ns++;
            __syncthreads();  // D: partner half of hbuf in place before next matvec
        }
    }
}

// ---------------------------------------------------------------------------
extern "C" void kernel_launch(void* const* d_in, const int* in_sizes, int n_in,
                              void* d_out, int out_size, void* d_ws, size_t ws_size,
                              hipStream_t stream)
{
    const float* x   = (const float*)d_in[0];  // (384,48,256)
    const float* hid = (const float*)d_in[1];  // (2,1,256)
    const float* wih = (const float*)d_in[2];  // (2,768,256)
    const float* whh = (const float*)d_in[3];  // (2,768,256)
    const float* bih = (const float*)d_in[4];  // (2,768)
    const float* bhh = (const float*)d_in[5];  // (2,768)
    const float* lw  = (const float*)d_in[6];  // (2,1,256)
    const float* lb  = (const float*)d_in[7];  // (2,1)
    float* out = (float*)d_out;

    float* ws   = (float*)d_ws;
    float* GI   = ws;                               // 18432*768
    float* Y0   = GI + (size_t)18432 * 768;         // 18432*256
    float* XH0  = Y0 + (size_t)18432 * 256;         // 48*2*256
    float* XH1  = XH0 + 48 * 512;
    float* PDX0 = XH1 + 48 * 512;                   // 48*2*2
    float* PDX1 = PDX0 + 192;
    int*   FLG0 = (int*)(PDX1 + 192);               // 48*2 ints per layer
    int*   FLG1 = FLG0 + 96;

    float* OUTy = out;                              // (384,48,256)
    float* HS   = out + (size_t)18432 * 256;        // (2,48,256)
    float* TU   = HS + 2 * 48 * 256;                // (48, 768)

    // flags must start < 1 regardless of workspace poison state
    hipMemsetAsync(FLG0, 0, 192 * sizeof(int), stream);

    dim3 ggrid(12, 144), gblk(256);
    gemm_nt<<<ggrid, gblk, 0, stream>>>(x, wih, bih, GI);
    rec_layer<<<96, 512, 0, stream>>>(GI, Y0, whh, bhh, lw, lb, hid,
                                      XH0, PDX0, FLG0, HS, TU);
    gemm_nt<<<ggrid, gblk, 0, stream>>>(Y0, wih + 196608, bih + 768, GI);
    rec_layer<<<96, 512, 0, stream>>>(GI, OUTy, whh + 196608, bhh + 768, lw + 256, lb + 1,
                                      hid + 256, XH1, PDX1, FLG1, HS + 12288, TU + 384);
}